// Round 1
// baseline (173.045 us; speedup 1.0000x reference)
//
#include <hip/hip_runtime.h>
#include <hip/hip_bf16.h>

// NAM_89739046683406: per-feature tiny MLP (B=32768, F=128, H=64)
// out(b) = sigmoid( bias + sum_f [ relu(relu(x[b,f]*w1[f]+b1[f]) @ w2[f] + b2[f]) . w3[f] + b3[f] ] )
// Strategy: bf16 MFMA grouped GEMM, one block = 128 rows x 1 feature.

#define B_SZ 32768
#define F_SZ 128
#define H_SZ 64
#define BM   128      // rows per block
#define WP   72       // padded Wt row (bf16 elems): 144B stride -> decent bank spread

typedef __attribute__((ext_vector_type(8))) short short8;   // bf16 x8 (4 VGPRs)
typedef __attribute__((ext_vector_type(4))) float floatx4;  // fp32 x4 acc

__device__ __forceinline__ short f2bf(float f) {
    union { float f; unsigned u; } v; v.f = f;
    unsigned r = (v.u + 0x7FFFu + ((v.u >> 16) & 1u)) >> 16;  // RNE
    return (short)r;
}

// MODE 0: part[f*B + r] = contrib         (partial buffer in ws, reduce kernel later)
// MODE 1: atomicAdd(&part[r], contrib)    (logit accumulator of B floats in ws)
// MODE 2: atomicAdd(&part[2r+1], contrib) (accumulate into out[:,1] slot)
template <int MODE>
__global__ __launch_bounds__(256, 3)
void nam_main(const float* __restrict__ x,  const float* __restrict__ w1,
              const float* __restrict__ b1, const float* __restrict__ w2,
              const float* __restrict__ b2, const float* __restrict__ w3,
              const float* __restrict__ b3, float* __restrict__ part)
{
    const int f    = blockIdx.x & (F_SZ - 1);
    const int r0   = (blockIdx.x >> 7) * BM;
    const int tid  = threadIdx.x;
    const int lane = tid & 63;
    const int wv   = tid >> 6;       // wave 0..3 -> rows [wv*32, wv*32+32)
    const int l15  = lane & 15;
    const int quad = lane >> 4;      // 0..3

    __shared__ __align__(16) unsigned short Wt[H_SZ * WP];   // Wt[g][h] bf16 (transposed w2[f])

    // ---- stage w2[f]^T into LDS as bf16 ----
    // unit u: h-pair hp=u>>4 (h=2hp,2hp+1), g-quad gq=u&15 (g=4gq..4gq+3)
    const float* w2f = w2 + (size_t)f * H_SZ * H_SZ;
    unsigned* w32 = (unsigned*)Wt;
    #pragma unroll
    for (int it = 0; it < 2; ++it) {
        int u  = tid + it * 256;       // 0..511
        int hp = u >> 4;               // 0..31
        int gq = u & 15;               // 0..15
        float4 a = *(const float4*)(w2f + (2 * hp)     * H_SZ + 4 * gq);
        float4 c = *(const float4*)(w2f + (2 * hp + 1) * H_SZ + 4 * gq);
        float av[4] = {a.x, a.y, a.z, a.w};
        float cv[4] = {c.x, c.y, c.z, c.w};
        #pragma unroll
        for (int j = 0; j < 4; ++j) {
            unsigned lo = (unsigned short)f2bf(av[j]);
            unsigned hi = (unsigned short)f2bf(cv[j]);
            w32[(((4 * gq + j) * WP) + 2 * hp) >> 1] = lo | (hi << 16);
        }
    }

    // ---- layer 1 directly into A fragments (registers, no LDS) ----
    // A[m=l15][k=quad*8+j]; row = r0 + wv*32 + mt*16 + l15, k = ks*32 + quad*8 + j
    float xv[2];
    #pragma unroll
    for (int mt = 0; mt < 2; ++mt)
        xv[mt] = x[(size_t)(r0 + wv * 32 + mt * 16 + l15) * F_SZ + f];

    short8 afrag[2][2];  // [mt][ks]
    #pragma unroll
    for (int ks = 0; ks < 2; ++ks) {
        const float4* w1p = (const float4*)(w1 + f * H_SZ + ks * 32 + quad * 8);
        const float4* b1p = (const float4*)(b1 + f * H_SZ + ks * 32 + quad * 8);
        float4 wA = w1p[0], wB = w1p[1];
        float4 bA = b1p[0], bB = b1p[1];
        float wk[8] = {wA.x, wA.y, wA.z, wA.w, wB.x, wB.y, wB.z, wB.w};
        float bk[8] = {bA.x, bA.y, bA.z, bA.w, bB.x, bB.y, bB.z, bB.w};
        #pragma unroll
        for (int mt = 0; mt < 2; ++mt) {
            #pragma unroll
            for (int j = 0; j < 8; ++j) {
                float h1 = fmaxf(fmaf(xv[mt], wk[j], bk[j]), 0.0f);
                afrag[mt][ks][j] = f2bf(h1);
            }
        }
    }

    __syncthreads();

    // ---- B fragments from LDS: B[k][n], n = nt*16 + l15, k = ks*32 + quad*8 + j ----
    short8 bfrag[4][2];
    #pragma unroll
    for (int nt = 0; nt < 4; ++nt)
        #pragma unroll
        for (int ks = 0; ks < 2; ++ks)
            bfrag[nt][ks] = *(const short8*)&Wt[(nt * 16 + l15) * WP + ks * 32 + quad * 8];

    // ---- MFMA: h2 = h1 @ w2[f] ----
    floatx4 acc[2][4];
    #pragma unroll
    for (int mt = 0; mt < 2; ++mt)
        #pragma unroll
        for (int nt = 0; nt < 4; ++nt)
            acc[mt][nt] = (floatx4)(0.0f);
    #pragma unroll
    for (int ks = 0; ks < 2; ++ks)
        #pragma unroll
        for (int mt = 0; mt < 2; ++mt)
            #pragma unroll
            for (int nt = 0; nt < 4; ++nt)
                acc[mt][nt] = __builtin_amdgcn_mfma_f32_16x16x32_bf16(
                    afrag[mt][ks], bfrag[nt][ks], acc[mt][nt], 0, 0, 0);

    // ---- epilogue: +b2, relu, .w3, reduce over 64 cols ----
    // C/D layout: col = nt*16 + l15, row = mt*16 + quad*4 + i
    float b2v[4], w3v[4];
    #pragma unroll
    for (int nt = 0; nt < 4; ++nt) {
        b2v[nt] = b2[f * H_SZ + nt * 16 + l15];
        w3v[nt] = w3[f * H_SZ + nt * 16 + l15];
    }
    float rs[2][4];
    #pragma unroll
    for (int mt = 0; mt < 2; ++mt)
        #pragma unroll
        for (int i = 0; i < 4; ++i) {
            float s = 0.0f;
            #pragma unroll
            for (int nt = 0; nt < 4; ++nt) {
                float h2v = fmaxf(acc[mt][nt][i] + b2v[nt], 0.0f);
                s = fmaf(h2v, w3v[nt], s);
            }
            rs[mt][i] = s;
        }
    #pragma unroll
    for (int m = 1; m < 16; m <<= 1) {
        #pragma unroll
        for (int mt = 0; mt < 2; ++mt)
            #pragma unroll
            for (int i = 0; i < 4; ++i)
                rs[mt][i] += __shfl_xor(rs[mt][i], m, 64);
    }

    if (l15 == 0) {
        float b3v = b3[f];
        #pragma unroll
        for (int mt = 0; mt < 2; ++mt)
            #pragma unroll
            for (int i = 0; i < 4; ++i) {
                int r   = r0 + wv * 32 + mt * 16 + quad * 4 + i;
                float c = rs[mt][i] + b3v;
                if (MODE == 0)      part[(size_t)f * B_SZ + r] = c;
                else if (MODE == 1) atomicAdd(&part[r], c);
                else                atomicAdd(&part[2 * r + 1], c);
            }
    }
}

__global__ __launch_bounds__(128)
void nam_reduce(const float* __restrict__ part, const float* __restrict__ bias,
                float* __restrict__ out)
{
    int b = blockIdx.x * 128 + threadIdx.x;
    float s = bias[0];
    #pragma unroll 16
    for (int f = 0; f < F_SZ; ++f) s += part[(size_t)f * B_SZ + b];
    float p = 1.0f / (1.0f + __expf(-s));
    ((float2*)out)[b] = make_float2(1.0f - p, p);
}

__global__ __launch_bounds__(256)
void nam_zero(float* __restrict__ p, int n)
{
    int i = blockIdx.x * 256 + threadIdx.x;
    if (i < n) p[i] = 0.0f;
}

__global__ __launch_bounds__(128)
void nam_final_ws(const float* __restrict__ logits, const float* __restrict__ bias,
                  float* __restrict__ out)
{
    int b = blockIdx.x * 128 + threadIdx.x;
    float s = logits[b] + bias[0];
    float p = 1.0f / (1.0f + __expf(-s));
    ((float2*)out)[b] = make_float2(1.0f - p, p);
}

__global__ __launch_bounds__(128)
void nam_final_inplace(const float* __restrict__ bias, float* __restrict__ out)
{
    int b = blockIdx.x * 128 + threadIdx.x;
    float s = out[2 * b + 1] + bias[0];
    float p = 1.0f / (1.0f + __expf(-s));
    ((float2*)out)[b] = make_float2(1.0f - p, p);
}

extern "C" void kernel_launch(void* const* d_in, const int* in_sizes, int n_in,
                              void* d_out, int out_size, void* d_ws, size_t ws_size,
                              hipStream_t stream)
{
    const float* x    = (const float*)d_in[0];
    const float* w1   = (const float*)d_in[1];
    const float* b1   = (const float*)d_in[2];
    const float* w2   = (const float*)d_in[3];
    const float* b2   = (const float*)d_in[4];
    const float* w3   = (const float*)d_in[5];
    const float* b3   = (const float*)d_in[6];
    const float* bias = (const float*)d_in[7];
    float* out = (float*)d_out;
    float* ws  = (float*)d_ws;

    const dim3 mainGrid((B_SZ / BM) * F_SZ);
    const dim3 mainBlk(256);

    if (ws_size >= (size_t)F_SZ * B_SZ * sizeof(float)) {
        // Tier 1: per-feature partials in ws, then coalesced reduce+sigmoid.
        nam_main<0><<<mainGrid, mainBlk, 0, stream>>>(x, w1, b1, w2, b2, w3, b3, ws);
        nam_reduce<<<dim3(B_SZ / 128), dim3(128), 0, stream>>>(ws, bias, out);
    } else if (ws_size >= (size_t)B_SZ * sizeof(float)) {
        // Tier 2: atomic logit accumulator (B floats) in ws.
        nam_zero<<<dim3(B_SZ / 256), dim3(256), 0, stream>>>(ws, B_SZ);
        nam_main<1><<<mainGrid, mainBlk, 0, stream>>>(x, w1, b1, w2, b2, w3, b3, ws);
        nam_final_ws<<<dim3(B_SZ / 128), dim3(128), 0, stream>>>(ws, bias, out);
    } else {
        // Tier 3: accumulate into out[:,1], finalize in place.
        nam_zero<<<dim3((2 * B_SZ) / 256), dim3(256), 0, stream>>>(out, 2 * B_SZ);
        nam_main<2><<<mainGrid, mainBlk, 0, stream>>>(x, w1, b1, w2, b2, w3, b3, out);
        nam_final_inplace<<<dim3(B_SZ / 128), dim3(128), 0, stream>>>(bias, out);
    }
}